// Round 3
// baseline (140.851 us; speedup 1.0000x reference)
//
#include <hip/hip_runtime.h>
#include <stdint.h>

// ---------------------------------------------------------------------------
// NeighborSearch: data[n,3], queries[m,3], radius scalar.
// Out layout (int32): [0, m*n)   neighbors_index (compacted front, -1 pad)
//                     [m*n, m*n+m+1) row_splits (exclusive prefix of counts)
//
// Fast path (n==m==8192):
//   K1: 2048 blocks x 256. Waves 0-2 fill -1s; wave 3 first counts 64 queries
//       over a 512-point range (thread-per-query, uniform point loads, no LDS,
//       no vmcnt coupling with the fill stores), then fills its share.
//       Role-by-wave => every XCD carries identical fill BW (the R2 parity
//       split starved HBM through only 4 of 8 XCDs).
//   K2: 128 blocks x 64 (thread-per-query): popcount masks -> counts,
//       wave scan + distributed cross-block prefix from per-wave sums,
//       write row_splits, emit compacted indices from masks.
// ---------------------------------------------------------------------------

#define N8 8192

__device__ __forceinline__ float next_up(float x) {
    return __uint_as_float(__float_as_uint(x) + 1u);
}
__device__ __forceinline__ float next_down(float x) {
    return __uint_as_float(__float_as_uint(x) - 1u);
}

// Largest float T with sqrt_rn(T) <= r (r > 0): (u <= T) <=> (sqrt(max(u,0)) <= r).
__device__ __forceinline__ float sq_threshold(float r) {
    float T = __fmul_rn(r, r);
    while (__fsqrt_rn(T) > r) T = next_down(T);
    while (__fsqrt_rn(next_up(T)) <= r) T = next_up(T);
    return T;
}

// Reference arithmetic exactly (no contraction):
// d2 = (dx*dx + dy*dy) + dz*dz ; dot = fma(qz,dz, fma(qy,dy, qx*dx))
// u  = (q2 + d2) - 2*dot
__device__ __forceinline__ float pair_metric(float qx, float qy, float qz, float q2,
                                             float dx, float dy, float dz) {
    float d2 = __fadd_rn(__fadd_rn(__fmul_rn(dx, dx), __fmul_rn(dy, dy)),
                         __fmul_rn(dz, dz));
    float dot = __builtin_fmaf(qz, dz, __builtin_fmaf(qy, dy, __fmul_rn(qx, dx)));
    return __fsub_rn(__fadd_rn(q2, d2), __fmul_rn(2.0f, dot));
}

// ========================= fast path (8192 x 8192) =========================

// Grid: 2048 x 256. masks2[c*8192+q] = 64-bit mask of points [c*64,(c+1)*64)
// for query q. qgrsum[qg*16+r] = total count of wave (qg,r).
__global__ __launch_bounds__(256) void fused_fill_count(
    const float* __restrict__ data, const float* __restrict__ queries,
    const float* __restrict__ radius_p, int* __restrict__ out_idx,
    unsigned long long* __restrict__ masks2, int* __restrict__ qgrsum) {
    int bid = blockIdx.x;
    int lane = threadIdx.x & 63;
    int wv = __builtin_amdgcn_readfirstlane(threadIdx.x >> 6);

    if (wv == 3) {
        // ---- count role: 64 queries x 512 points ----
        int qg = bid >> 4;          // query group 0..127
        int r  = bid & 15;          // point range 0..15
        int q = qg * 64 + lane;
        float rad = radius_p[0];
        float T = sq_threshold(rad);
        float qx = queries[3 * q + 0], qy = queries[3 * q + 1], qz = queries[3 * q + 2];
        float q2 = __fadd_rn(__fadd_rn(__fmul_rn(qx, qx), __fmul_rn(qy, qy)),
                             __fmul_rn(qz, qz));
        int cnt = 0;
        const int j0 = r * 512;
        for (int cc = 0; cc < 8; ++cc) {
            unsigned long long mk = 0ull;
#pragma unroll 8
            for (int jj = 0; jj < 64; ++jj) {
                int j = j0 + cc * 64 + jj;           // wave-uniform
                float dx = data[3 * j + 0];
                float dy = data[3 * j + 1];
                float dz = data[3 * j + 2];
                float u = pair_metric(qx, qy, qz, q2, dx, dy, dz);
                if (u <= T) mk |= (1ull << jj);
            }
            cnt += __popcll(mk);
            masks2[(size_t)(r * 8 + cc) * N8 + q] = mk;   // coalesced 512B
        }
        int s = cnt;
        for (int off = 32; off > 0; off >>= 1) s += __shfl_down(s, off, 64);
        if (lane == 0) qgrsum[qg * 16 + r] = s;
    }

    // ---- fill role: all 4 waves write -1s (wave 3 after counting) ----
    int4* out4 = (int4*)out_idx;
    size_t fw = (size_t)bid * 4 + wv;                 // 0..8191
    const int4 v = make_int4(-1, -1, -1, -1);
#pragma unroll 4
    for (int k = 0; k < 32; ++k) {
        out4[(fw + (size_t)k * 8192) * 64 + lane] = v;  // 1KB contiguous/instr
    }
}

// Grid: 128 x 64 (one wave). Thread t of block b owns query q = b*64+t.
__global__ __launch_bounds__(64) void scan_emit(
    const unsigned long long* __restrict__ masks2,
    const int* __restrict__ qgrsum,
    int* __restrict__ out_idx, int* __restrict__ rs) {
    int t = threadIdx.x;
    int b = blockIdx.x;
    int q = b * 64 + t;

    // A: per-query count from masks
    int cq = 0;
    for (int c = 0; c < 128; ++c)
        cq += __popcll(masks2[(size_t)c * N8 + q]);

    // B: wave inclusive scan -> exclusive within this query group
    int inc = cq;
    for (int off = 1; off < 64; off <<= 1) {
        int w = __shfl_up(inc, off, 64);
        if (t >= off) inc += w;
    }
    int ex = inc - cq;

    // C: cross-group prefix from per-wave sums (qg < b <=> idx < 16b)
    int sp = 0, sa = 0;
    int lim = 16 * b;
    for (int i = t; i < 2048; i += 64) {
        int v = qgrsum[i];
        sa += v;
        if (i < lim) sp += v;
    }
    for (int off = 32; off > 0; off >>= 1) {
        sp += __shfl_down(sp, off, 64);
        sa += __shfl_down(sa, off, 64);
    }
    sp = __shfl(sp, 0, 64);
    sa = __shfl(sa, 0, 64);

    int base = sp + ex;
    rs[q] = base;
    if (q == N8 - 1) rs[N8] = sa;

    // D: emit compacted indices (ascending c, ascending bit = row-major order)
    int pos = base;
    for (int c = 0; c < 128; ++c) {
        unsigned long long m = masks2[(size_t)c * N8 + q];
        int jb = c * 64;
        while (m) {
            int bt = __builtin_ctzll(m);
            out_idx[pos++] = jb + bt;
            m &= m - 1;
        }
    }
}

// ====================== generic fallback (round-1 path) ======================

__global__ __launch_bounds__(256) void fill_kernel(int* __restrict__ out, size_t total) {
    size_t n4 = total >> 2;
    int4* out4 = (int4*)out;
    size_t i = (size_t)blockIdx.x * blockDim.x + threadIdx.x;
    size_t stride = (size_t)gridDim.x * blockDim.x;
    const int4 v = make_int4(-1, -1, -1, -1);
    for (; i < n4; i += stride) out4[i] = v;
    if (blockIdx.x == 0 && threadIdx.x == 0) {
        for (size_t k = n4 << 2; k < total; ++k) out[k] = -1;
    }
}

__global__ __launch_bounds__(256) void count_kernel(
    const float* __restrict__ data, const float* __restrict__ queries,
    const float* __restrict__ radius_p, int n, int m, int* __restrict__ counts) {
    int q = (blockIdx.x * blockDim.x + threadIdx.x) >> 6;
    int lane = threadIdx.x & 63;
    if (q >= m) return;
    float r = radius_p[0];
    float T = sq_threshold(r);
    float qx = queries[3 * q + 0], qy = queries[3 * q + 1], qz = queries[3 * q + 2];
    float q2 = __fadd_rn(__fadd_rn(__fmul_rn(qx, qx), __fmul_rn(qy, qy)),
                         __fmul_rn(qz, qz));
    int cnt = 0;
    for (int j = lane; j < n; j += 64) {
        float u = pair_metric(qx, qy, qz, q2, data[3 * j], data[3 * j + 1], data[3 * j + 2]);
        if (u <= T) cnt++;
    }
    for (int off = 32; off > 0; off >>= 1) cnt += __shfl_down(cnt, off, 64);
    if (lane == 0) counts[q] = cnt;
}

__global__ __launch_bounds__(1024) void scan_kernel2(const int* __restrict__ counts,
                                                     int* __restrict__ rs, int m) {
    __shared__ int part[1024];
    int t = threadIdx.x;
    int base = t * 8;
    int c[8];
    int s = 0;
    for (int k = 0; k < 8; ++k) {
        int p = base + k;
        c[k] = (p < m) ? counts[p] : 0;
        s += c[k];
    }
    part[t] = s;
    __syncthreads();
    for (int off = 1; off < 1024; off <<= 1) {
        int v = 0;
        if (t >= off) v = part[t - off];
        __syncthreads();
        if (t >= off) part[t] += v;
        __syncthreads();
    }
    int run = (t == 0) ? 0 : part[t - 1];
    for (int k = 0; k < 8; ++k) {
        int p = base + k;
        if (p < m) rs[p] = run;
        run += c[k];
    }
    if (t == 1023) rs[m] = part[1023];
}

__global__ __launch_bounds__(256) void emit_kernel(
    const float* __restrict__ data, const float* __restrict__ queries,
    const float* __restrict__ radius_p, int n, int m,
    const int* __restrict__ row_splits, int* __restrict__ out_idx) {
    int q = (blockIdx.x * blockDim.x + threadIdx.x) >> 6;
    int lane = threadIdx.x & 63;
    if (q >= m) return;
    float r = radius_p[0];
    float T = sq_threshold(r);
    float qx = queries[3 * q + 0], qy = queries[3 * q + 1], qz = queries[3 * q + 2];
    float q2 = __fadd_rn(__fadd_rn(__fmul_rn(qx, qx), __fmul_rn(qy, qy)),
                         __fmul_rn(qz, qz));
    int base = row_splits[q];
    unsigned long long lane_mask_lt = (lane == 0) ? 0ULL : (~0ULL >> (64 - lane));
    for (int j0 = 0; j0 < n; j0 += 64) {
        int j = j0 + lane;
        bool pred = false;
        if (j < n) {
            float u = pair_metric(qx, qy, qz, q2, data[3 * j], data[3 * j + 1], data[3 * j + 2]);
            pred = (u <= T);
        }
        unsigned long long mask = __ballot(pred);
        if (pred) {
            int pos = base + __popcll(mask & lane_mask_lt);
            out_idx[pos] = j;
        }
        base += __popcll(mask);
    }
}

// ===========================================================================

extern "C" void kernel_launch(void* const* d_in, const int* in_sizes, int n_in,
                              void* d_out, int out_size, void* d_ws, size_t ws_size,
                              hipStream_t stream) {
    const float* data = (const float*)d_in[0];
    const float* queries = (const float*)d_in[1];
    const float* radius = (const float*)d_in[2];
    int n = in_sizes[0] / 3;
    int m = in_sizes[1] / 3;
    int* out = (int*)d_out;
    size_t idx_count = (size_t)m * (size_t)n;
    int* row = out + idx_count;  // m+1 ints

    size_t need = (size_t)N8 * 128 * 8 + 2048 * 4;  // masks2 + qgrsum = 8.01MB
    bool fast = (n == N8) && (m == N8) && (ws_size >= need);

    if (fast) {
        unsigned long long* masks2 = (unsigned long long*)d_ws;
        int* qgrsum = (int*)((char*)d_ws + (size_t)N8 * 128 * 8);
        fused_fill_count<<<2048, 256, 0, stream>>>(data, queries, radius, out,
                                                   masks2, qgrsum);
        scan_emit<<<128, 64, 0, stream>>>(masks2, qgrsum, out, row);
    } else {
        fill_kernel<<<2048, 256, 0, stream>>>(out, idx_count);
        int blocks = (m * 64 + 255) / 256;
        count_kernel<<<blocks, 256, 0, stream>>>(data, queries, radius, n, m, row);
        scan_kernel2<<<1, 1024, 0, stream>>>(row, row, m);
        emit_kernel<<<blocks, 256, 0, stream>>>(data, queries, radius, n, m, row, out);
    }
}

// Round 4
// 85.887 us; speedup vs baseline: 1.6400x; 1.6400x over previous
//
#include <hip/hip_runtime.h>
#include <stdint.h>

// ---------------------------------------------------------------------------
// NeighborSearch: data[n,3], queries[m,3], radius scalar.
// Out layout (int32): [0, m*n)   neighbors_index (compacted front, -1 pad)
//                     [m*n, m*n+m+1) row_splits (exclusive prefix of counts)
//
// Fast path (n==m==8192, ws >= 8.5MB):
//   K1 fused: role by GROUPS OF 8 blocks ((bid>>3)&1) so both roles spread
//             evenly across the 8 XCDs (R2's bid&1 split put all fill blocks
//             on XCDs {0,2,4,6} -> half-fabric write BW).
//             Fill role: -1-fill the index region (write-BW-bound).
//             Count role: count + build per-query 64-bit chunk masks in d_ws.
//   K2 scan: exclusive prefix of counts -> row_splits.
//   K3 emit: read masks, wave prefix of popcounts, write compacted indices.
// ---------------------------------------------------------------------------

__device__ __forceinline__ float next_up(float x) {
    return __uint_as_float(__float_as_uint(x) + 1u);
}
__device__ __forceinline__ float next_down(float x) {
    return __uint_as_float(__float_as_uint(x) - 1u);
}

// Largest float T such that correctly-rounded sqrt(T) <= r (r > 0).
// (u <= T) <=> (sqrt_rn(max(u,0)) <= r) for all u, since sqrt_rn is monotone.
__device__ __forceinline__ float sq_threshold(float r) {
    float T = __fmul_rn(r, r);
    while (__fsqrt_rn(T) > r) T = next_down(T);
    while (__fsqrt_rn(next_up(T)) <= r) T = next_up(T);
    return T;
}

// Reference arithmetic, exactly (no contraction):
// d2 = (dx*dx + dy*dy) + dz*dz ; dot = fma(qz,dz, fma(qy,dy, qx*dx))
// u  = (q2 + d2) - 2*dot
__device__ __forceinline__ float pair_metric_d2(float qx, float qy, float qz,
                                                float q2, float dx, float dy,
                                                float dz, float d2) {
    float dot = __builtin_fmaf(qz, dz, __builtin_fmaf(qy, dy, __fmul_rn(qx, dx)));
    return __fsub_rn(__fadd_rn(q2, d2), __fmul_rn(2.0f, dot));
}
__device__ __forceinline__ float pair_metric(float qx, float qy, float qz, float q2,
                                             float dx, float dy, float dz) {
    float d2 = __fadd_rn(__fadd_rn(__fmul_rn(dx, dx), __fmul_rn(dy, dy)),
                         __fmul_rn(dz, dz));
    return pair_metric_d2(qx, qy, qz, q2, dx, dy, dz, d2);
}

// ========================= fast path (8192 x 8192) =========================

// Grid: 4096 blocks x 256 threads. Role by (bid>>3)&1: alternating groups of
// 8 consecutive blocks -> XCD-balanced for both roles, both co-resident.
__global__ __launch_bounds__(256) void fused_fill_count(
    const float* __restrict__ data, const float* __restrict__ queries,
    const float* __restrict__ radius_p, int* __restrict__ out_idx,
    unsigned long long* __restrict__ masks, int* __restrict__ counts) {
    constexpr int N = 8192;
    __shared__ float4 pts[512];

    int bid = blockIdx.x;
    int role = (bid >> 3) & 1;
    int rb = ((bid >> 4) << 3) | (bid & 7);   // 0..2047 within each role

    if (role == 0) {
        // ---- fill role: -1 the whole index region (8192*8192 ints) ----
        int4* out4 = (int4*)out_idx;
        const size_t n4 = (size_t)N * N / 4;          // 16,777,216
        size_t i = (size_t)rb * 256 + threadIdx.x;
        const size_t stride = 2048ull * 256ull;
        const int4 v = make_int4(-1, -1, -1, -1);
        for (; i < n4; i += stride) out4[i] = v;
        return;
    }

    // ---- count role: wave = one query, lanes stride data chunks ----
    int wave = threadIdx.x >> 6;
    int lane = threadIdx.x & 63;
    int q = rb * 4 + wave;

    float r = radius_p[0];
    float T = sq_threshold(r);
    float qx = queries[3 * q + 0], qy = queries[3 * q + 1], qz = queries[3 * q + 2];
    float q2 = __fadd_rn(__fadd_rn(__fmul_rn(qx, qx), __fmul_rn(qy, qy)),
                         __fmul_rn(qz, qz));

    unsigned long long mlo = 0, mhi = 0;  // this wave's mask for chunk c is
    int cnt = 0;                          // parked in lane (c & 63)'s mlo/mhi

    for (int rd = 0; rd < 16; ++rd) {     // 16 rounds x 512 points
        int p0 = rd * 512;
        __syncthreads();
        for (int p = threadIdx.x; p < 512; p += 256) {
            float dx = data[3 * (p0 + p) + 0];
            float dy = data[3 * (p0 + p) + 1];
            float dz = data[3 * (p0 + p) + 2];
            float d2 = __fadd_rn(__fadd_rn(__fmul_rn(dx, dx), __fmul_rn(dy, dy)),
                                 __fmul_rn(dz, dz));
            pts[p] = make_float4(dx, dy, dz, d2);
        }
        __syncthreads();
#pragma unroll
        for (int cc = 0; cc < 8; ++cc) {
            float4 d = pts[cc * 64 + lane];
            float u = pair_metric_d2(qx, qy, qz, q2, d.x, d.y, d.z, d.w);
            unsigned long long mask = __ballot(u <= T);
            int c = rd * 8 + cc;
            if (lane == (c & 63)) {
                if (c < 64) mlo = mask; else mhi = mask;
            }
            cnt += __popcll(mask);
        }
    }
    masks[(size_t)q * 128 + lane] = mlo;        // coalesced 512B per wave
    masks[(size_t)q * 128 + 64 + lane] = mhi;
    if (lane == 0) counts[q] = cnt;
}

// Exclusive scan of counts[0..m) -> rs[0..m]. One block, m <= 8192.
__global__ __launch_bounds__(1024) void scan_kernel2(const int* __restrict__ counts,
                                                     int* __restrict__ rs, int m) {
    __shared__ int part[1024];
    int t = threadIdx.x;
    int base = t * 8;
    int c[8];
    int s = 0;
    for (int k = 0; k < 8; ++k) {
        int p = base + k;
        c[k] = (p < m) ? counts[p] : 0;
        s += c[k];
    }
    part[t] = s;
    __syncthreads();
    for (int off = 1; off < 1024; off <<= 1) {
        int v = 0;
        if (t >= off) v = part[t - off];
        __syncthreads();
        if (t >= off) part[t] += v;
        __syncthreads();
    }
    int run = (t == 0) ? 0 : part[t - 1];
    for (int k = 0; k < 8; ++k) {
        int p = base + k;
        if (p < m) rs[p] = run;
        run += c[k];
    }
    if (t == 1023) rs[m] = part[1023];
}

// Wave per query: read 128 chunk masks, prefix popcounts, write indices.
__global__ __launch_bounds__(256) void emit_from_masks(
    const unsigned long long* __restrict__ masks, const int* __restrict__ rs,
    int* __restrict__ out_idx) {
    int wave = threadIdx.x >> 6;
    int lane = threadIdx.x & 63;
    int q = blockIdx.x * 4 + wave;

    unsigned long long lo = masks[(size_t)q * 128 + lane];
    unsigned long long hi = masks[(size_t)q * 128 + 64 + lane];
    int plo = __popcll(lo), phi = __popcll(hi);
    int ilo = plo, ihi = phi;
    for (int off = 1; off < 64; off <<= 1) {
        int a = __shfl_up(ilo, off, 64);
        int b = __shfl_up(ihi, off, 64);
        if (lane >= off) { ilo += a; ihi += b; }
    }
    int total_lo = __shfl(ilo, 63, 64);
    int base = rs[q];
    int pos_lo = base + ilo - plo;
    int pos_hi = base + total_lo + ihi - phi;
    int jb_lo = lane * 64, jb_hi = (64 + lane) * 64;
    while (lo) {
        int b = __builtin_ctzll(lo);
        out_idx[pos_lo++] = jb_lo + b;
        lo &= lo - 1;
    }
    while (hi) {
        int b = __builtin_ctzll(hi);
        out_idx[pos_hi++] = jb_hi + b;
        hi &= hi - 1;
    }
}

// ====================== generic fallback (round-1 path) ======================

__global__ __launch_bounds__(256) void fill_kernel(int* __restrict__ out, size_t total) {
    size_t n4 = total >> 2;
    int4* out4 = (int4*)out;
    size_t i = (size_t)blockIdx.x * blockDim.x + threadIdx.x;
    size_t stride = (size_t)gridDim.x * blockDim.x;
    const int4 v = make_int4(-1, -1, -1, -1);
    for (; i < n4; i += stride) out4[i] = v;
    if (blockIdx.x == 0 && threadIdx.x == 0) {
        for (size_t k = n4 << 2; k < total; ++k) out[k] = -1;
    }
}

__global__ __launch_bounds__(256) void count_kernel(
    const float* __restrict__ data, const float* __restrict__ queries,
    const float* __restrict__ radius_p, int n, int m, int* __restrict__ counts) {
    int q = (blockIdx.x * blockDim.x + threadIdx.x) >> 6;
    int lane = threadIdx.x & 63;
    if (q >= m) return;
    float r = radius_p[0];
    float T = sq_threshold(r);
    float qx = queries[3 * q + 0], qy = queries[3 * q + 1], qz = queries[3 * q + 2];
    float q2 = __fadd_rn(__fadd_rn(__fmul_rn(qx, qx), __fmul_rn(qy, qy)),
                         __fmul_rn(qz, qz));
    int cnt = 0;
    for (int j = lane; j < n; j += 64) {
        float u = pair_metric(qx, qy, qz, q2, data[3 * j], data[3 * j + 1], data[3 * j + 2]);
        if (u <= T) cnt++;
    }
    for (int off = 32; off > 0; off >>= 1) cnt += __shfl_down(cnt, off, 64);
    if (lane == 0) counts[q] = cnt;
}

__global__ __launch_bounds__(256) void emit_kernel(
    const float* __restrict__ data, const float* __restrict__ queries,
    const float* __restrict__ radius_p, int n, int m,
    const int* __restrict__ row_splits, int* __restrict__ out_idx) {
    int q = (blockIdx.x * blockDim.x + threadIdx.x) >> 6;
    int lane = threadIdx.x & 63;
    if (q >= m) return;
    float r = radius_p[0];
    float T = sq_threshold(r);
    float qx = queries[3 * q + 0], qy = queries[3 * q + 1], qz = queries[3 * q + 2];
    float q2 = __fadd_rn(__fadd_rn(__fmul_rn(qx, qx), __fmul_rn(qy, qy)),
                         __fmul_rn(qz, qz));
    int base = row_splits[q];
    unsigned long long lane_mask_lt = (lane == 0) ? 0ULL : (~0ULL >> (64 - lane));
    for (int j0 = 0; j0 < n; j0 += 64) {
        int j = j0 + lane;
        bool pred = false;
        if (j < n) {
            float u = pair_metric(qx, qy, qz, q2, data[3 * j], data[3 * j + 1], data[3 * j + 2]);
            pred = (u <= T);
        }
        unsigned long long mask = __ballot(pred);
        if (pred) {
            int pos = base + __popcll(mask & lane_mask_lt);
            out_idx[pos] = j;
        }
        base += __popcll(mask);
    }
}

// ===========================================================================

extern "C" void kernel_launch(void* const* d_in, const int* in_sizes, int n_in,
                              void* d_out, int out_size, void* d_ws, size_t ws_size,
                              hipStream_t stream) {
    const float* data = (const float*)d_in[0];
    const float* queries = (const float*)d_in[1];
    const float* radius = (const float*)d_in[2];
    int n = in_sizes[0] / 3;
    int m = in_sizes[1] / 3;
    int* out = (int*)d_out;
    size_t idx_count = (size_t)m * (size_t)n;
    int* row = out + idx_count;  // m+1 ints

    size_t need = (size_t)m * 128 * 8 + (size_t)m * 4;
    bool fast = (n == 8192) && (m == 8192) && (ws_size >= need);

    if (fast) {
        unsigned long long* masks = (unsigned long long*)d_ws;
        int* counts = (int*)((char*)d_ws + (size_t)m * 128 * 8);
        // 2048 fill blocks + 2048 count blocks, interleaved in groups of 8
        fused_fill_count<<<4096, 256, 0, stream>>>(data, queries, radius, out,
                                                   masks, counts);
        scan_kernel2<<<1, 1024, 0, stream>>>(counts, row, m);
        emit_from_masks<<<m / 4, 256, 0, stream>>>(masks, row, out);
    } else {
        fill_kernel<<<2048, 256, 0, stream>>>(out, idx_count);
        int blocks = (m * 64 + 255) / 256;
        count_kernel<<<blocks, 256, 0, stream>>>(data, queries, radius, n, m, row);
        scan_kernel2<<<1, 1024, 0, stream>>>(row, row, m);
        emit_kernel<<<blocks, 256, 0, stream>>>(data, queries, radius, n, m, row, out);
    }
}